// Round 9
// baseline (725.951 us; speedup 1.0000x reference)
//
#include <hip/hip_runtime.h>

#define N_NODES 100000
#define N_EDGES 1600000
#define D 64

#define BN 64                               // nodes per bucket
#define NBUCK ((N_NODES + BN - 1) / BN)     // 1563
#define CHW 256                             // binning chunks (clustered = best measured)
#define CH ((N_EDGES + CHW - 1) / CHW)      // 6250 edges per chunk
#define CITER 13                            // ceil(CH/512)
#define CAP 2048                            // fixed bucket capacity in coarse
#define PAD 16                              // cursor padding (64 B) -> per-line atomics
#define OVFMAX 32768                        // global overflow list (never used in practice)
#define GEMM_THREADS (N_NODES * 16 / 2)     // 800000: 16 threads per row-pair
#define GEMM_BLKS ((GEMM_THREADS + 511) / 512)  // 1563
#define NBLK (CHW + GEMM_BLKS)              // 1819
#define GT 512                              // bgather threads
#define STR 67                              // acc row stride (floats, odd -> bank spread)

static __device__ __forceinline__ unsigned short f2bf(float f) {
    unsigned u = __float_as_uint(f);
    u += 0x7FFFu + ((u >> 16) & 1u);
    return (unsigned short)(u >> 16);
}
static __device__ __forceinline__ float bf2f(unsigned short h) {
    return __uint_as_float((unsigned)h << 16);
}

// ---------------- fused main: blocks [0,CHW) bin edges, blocks [CHW,..) do GEMM ----
// EXACT round-2 structure (best measured: main = 58.8-60.3 us over 4 runs). FROZEN.
__global__ __launch_bounds__(512) void gcn_main(const float* __restrict__ x,
                                                const float* __restrict__ w,
                                                unsigned short* __restrict__ support,
                                                const int* __restrict__ src,
                                                const int* __restrict__ dst,
                                                const float* __restrict__ adj,
                                                int* __restrict__ gcur,
                                                int* __restrict__ ovfcnt,
                                                int4* __restrict__ ovflist,
                                                int2* __restrict__ coarse) {
    __shared__ __align__(16) char smem[16384];
    int tid = threadIdx.x;
    int bid = blockIdx.x;

    if (bid < CHW) {
        // ---- binning role (register-staged chunk, per-block run reservation) ----
        int* h = (int*)smem;            // NBUCK counts
        int* cur = h + NBUCK;           // NBUCK cursors
        for (int i = tid; i < NBUCK; i += 512) h[i] = 0;
        __syncthreads();

        int e0 = bid * CH, e1 = min(e0 + CH, N_EDGES);
        int dreg[CITER], sreg[CITER];
        float areg[CITER];
        #pragma unroll
        for (int it = 0; it < CITER; ++it) {
            int e = e0 + tid + it * 512;
            dreg[it] = -1;
            if (e < e1) {
                dreg[it] = __builtin_nontemporal_load(&dst[e]);
                sreg[it] = __builtin_nontemporal_load(&src[e]);
                areg[it] = __builtin_nontemporal_load(&adj[e]);
                atomicAdd(&h[dreg[it] >> 6], 1);
            }
        }
        __syncthreads();

        for (int c = tid; c < NBUCK; c += 512) {
            int hc = h[c];
            if (hc) cur[c] = atomicAdd(&gcur[c * PAD], hc);
        }
        __syncthreads();

        #pragma unroll
        for (int it = 0; it < CITER; ++it) {
            if (dreg[it] >= 0) {
                int c = dreg[it] >> 6;
                int pos = atomicAdd(&cur[c], 1);
                if (pos < CAP) {
                    coarse[c * CAP + pos] =
                        make_int2(sreg[it] | ((dreg[it] & 63) << 17),
                                  __float_as_int(areg[it]));
                } else {
                    int op = atomicAdd(ovfcnt, 1);
                    if (op < OVFMAX)
                        ovflist[op] = make_int4(sreg[it], dreg[it],
                                                __float_as_int(areg[it]), 0);
                }
            }
        }
    } else {
        // ---- GEMM role: support(bf16) = X @ W ----
        float4* wsh = (float4*)smem;    // 64x16 float4 = 16 KB
        const float4* w4 = (const float4*)w;
        for (int i = tid; i < 64 * 16; i += 512) wsh[i] = w4[i];
        __syncthreads();

        int idx = (bid - CHW) * 512 + tid;
        if (idx < GEMM_THREADS) {
            int rowpair = idx >> 4;
            int c4 = idx & 15;
            long r0 = (long)rowpair * 2;
            const float4* xr0 = (const float4*)(x + r0 * D);
            const float4* xr1 = (const float4*)(x + (r0 + 1) * D);

            float4 a0 = make_float4(0.f, 0.f, 0.f, 0.f);
            float4 a1 = make_float4(0.f, 0.f, 0.f, 0.f);
            #pragma unroll 4
            for (int k4 = 0; k4 < 16; ++k4) {
                float4 xv0 = xr0[k4];
                float4 xv1 = xr1[k4];
                float4 w0 = wsh[(4 * k4 + 0) * 16 + c4];
                float4 w1 = wsh[(4 * k4 + 1) * 16 + c4];
                float4 w2 = wsh[(4 * k4 + 2) * 16 + c4];
                float4 w3 = wsh[(4 * k4 + 3) * 16 + c4];
                a0 += w0 * xv0.x + w1 * xv0.y + w2 * xv0.z + w3 * xv0.w;
                a1 += w0 * xv1.x + w1 * xv1.y + w2 * xv1.z + w3 * xv1.w;
            }
            ushort4* s4 = (ushort4*)support;
            s4[r0 * 16 + c4] = make_ushort4(f2bf(a0.x), f2bf(a0.y), f2bf(a0.z), f2bf(a0.w));
            s4[(r0 + 1) * 16 + c4] = make_ushort4(f2bf(a1.x), f2bf(a1.y), f2bf(a1.z), f2bf(a1.w));
        }
    }
}

// ---------------- bgather v3: edge-parallel, LDS f32 accumulation (ds_add_f32) ----
// R5 concept, lowering bug fixed: atomics index the __shared__ array DIRECTLY
// (no derived generic pointer) via __hip_atomic_fetch_add workgroup-scope relaxed
// -> ds_add_f32 (no return). Single coarse pass, no sort, no per-node serial
// chains: every iteration independent -> maximal memory-level parallelism.
__global__ __launch_bounds__(GT) void gcn_bgather(const unsigned short* __restrict__ support,
                                                  const int2* __restrict__ coarse,
                                                  const int* __restrict__ gcur,
                                                  const int* __restrict__ ovfcnt,
                                                  const int4* __restrict__ ovflist,
                                                  const float* __restrict__ bias,
                                                  float* __restrict__ out) {
    __shared__ float accS[BN * STR];        // 64 x 67 f32 = 17,168 B

    int tid = threadIdx.x;
    int b = blockIdx.x;
    int tot = min(gcur[b * PAD], CAP);      // bucket edge count (post-binning cursor)
    const int2* ce = coarse + (long)b * CAP;

    for (int i = tid; i < BN * STR; i += GT) accS[i] = 0.f;
    __syncthreads();

    int g = tid >> 4;        // edge group 0..31
    int L = tid & 15;        // feature quad 0..15
    const uint2* sup2 = (const uint2*)support;     // 8 B = 4 bf16 features

    #pragma unroll 4
    for (int e = g; e < tot; e += 32) {
        int2 ed = ce[e];                    // 16 lanes same addr (broadcast)
        int nl = (ed.x >> 17) & 63;
        float wgt = __int_as_float(ed.y);
        uint2 p = sup2[(long)(ed.x & 0x1FFFF) * 16 + L];
        int ab = nl * STR + L * 4;
        __hip_atomic_fetch_add(&accS[ab + 0], wgt * __uint_as_float(p.x << 16),
                               __ATOMIC_RELAXED, __HIP_MEMORY_SCOPE_WORKGROUP);
        __hip_atomic_fetch_add(&accS[ab + 1], wgt * __uint_as_float(p.x & 0xFFFF0000u),
                               __ATOMIC_RELAXED, __HIP_MEMORY_SCOPE_WORKGROUP);
        __hip_atomic_fetch_add(&accS[ab + 2], wgt * __uint_as_float(p.y << 16),
                               __ATOMIC_RELAXED, __HIP_MEMORY_SCOPE_WORKGROUP);
        __hip_atomic_fetch_add(&accS[ab + 3], wgt * __uint_as_float(p.y & 0xFFFF0000u),
                               __ATOMIC_RELAXED, __HIP_MEMORY_SCOPE_WORKGROUP);
    }
    __syncthreads();

    // epilogue: acc + bias -> out (coalesced float4 stores, scalar LDS reads)
    const float4* bias4 = (const float4*)bias;
    float4* out4 = (float4*)out;
    for (int i = tid; i < BN * 16; i += GT) {
        int nl = i >> 4, q = i & 15;
        int n = b * BN + nl;
        if (n < N_NODES) {
            float4 bv = bias4[q];
            int ab = nl * STR + q * 4;
            out4[(long)n * 16 + q] = make_float4(accS[ab + 0] + bv.x,
                                                 accS[ab + 1] + bv.y,
                                                 accS[ab + 2] + bv.z,
                                                 accS[ab + 3] + bv.w);
        }
    }

    // overflow tail (correctness only; ovfcnt == 0 for this input -> one load)
    __syncthreads();
    int lane = tid & 63, wv = tid >> 6;
    int no = min(*ovfcnt, OVFMAX);
    for (int i = wv; i < no; i += GT / 64) {
        int4 ed = ovflist[i];
        if ((ed.y >> 6) == b) {
            float v = __int_as_float(ed.z) * bf2f(support[(long)ed.x * D + lane]);
            atomicAdd(&out[(long)ed.y * D + lane], v);
        }
    }
}

extern "C" void kernel_launch(void* const* d_in, const int* in_sizes, int n_in,
                              void* d_out, int out_size, void* d_ws, size_t ws_size,
                              hipStream_t stream) {
    const float* x      = (const float*)d_in[0];
    const float* weight = (const float*)d_in[1];
    const float* bias   = (const float*)d_in[2];
    const float* adj    = (const float*)d_in[3];
    const int*   src    = (const int*)d_in[4];
    const int*   dst    = (const int*)d_in[5];
    float* out = (float*)d_out;

    unsigned short* support = (unsigned short*)d_ws;          // 12,800,000 B
    int2* coarse = (int2*)(support + (long)N_NODES * D);      // NBUCK*CAP*8 = 25,608,192 B
    int*  gcur   = (int*)(coarse + (long)NBUCK * CAP);        // NBUCK*PAD*4 = 100,032 B
    int*  ovfcnt = gcur + NBUCK * PAD;                        // 16 B reserved
    int4* ovflist = (int4*)(ovfcnt + 4);                      // 524,288 B

    hipMemsetAsync(gcur, 0, NBUCK * PAD * sizeof(int) + 16, stream);
    hipLaunchKernelGGL(gcn_main, dim3(NBLK), dim3(512), 0, stream,
                       x, weight, support, src, dst, adj, gcur, ovfcnt, ovflist, coarse);
    hipLaunchKernelGGL(gcn_bgather, dim3(NBUCK), dim3(GT), 0, stream,
                       support, coarse, gcur, ovfcnt, ovflist, bias, out);
}

// Round 10
// 169.127 us; speedup vs baseline: 4.2923x; 4.2923x over previous
//
#include <hip/hip_runtime.h>

#define N_NODES 100000
#define N_EDGES 1600000
#define D 64

#define BN 64                               // nodes per bucket
#define NBUCK ((N_NODES + BN - 1) / BN)     // 1563
#define CHW 256                             // binning chunks (clustered = best measured)
#define CH ((N_EDGES + CHW - 1) / CHW)      // 6250 edges per chunk
#define CITER 13                            // ceil(CH/512)
#define CAP 2048                            // fixed bucket capacity in coarse
#define SMAX 2048                           // LDS edge capacity (== CAP)
#define PAD 16                              // cursor padding (64 B) -> per-line atomics
#define OVFMAX 32768                        // global overflow list (never used in practice)
#define GEMM_THREADS (N_NODES * 16 / 2)     // 800000: 16 threads per row-pair
#define GEMM_BLKS ((GEMM_THREADS + 511) / 512)  // 1563
#define NBLK (CHW + GEMM_BLKS)              // 1819
#define GT 512                              // bgather threads (8 waves x 8 nodes)

static __device__ __forceinline__ unsigned short f2bf(float f) {
    unsigned u = __float_as_uint(f);
    u += 0x7FFFu + ((u >> 16) & 1u);
    return (unsigned short)(u >> 16);
}
static __device__ __forceinline__ float bf2f(unsigned short h) {
    return __uint_as_float((unsigned)h << 16);
}

// ---------------- fused main: blocks [0,CHW) bin edges, blocks [CHW,..) do GEMM ----
// EXACT round-2 structure (best measured: main = 58.8-60.3 us over 5 runs). FROZEN.
__global__ __launch_bounds__(512) void gcn_main(const float* __restrict__ x,
                                                const float* __restrict__ w,
                                                unsigned short* __restrict__ support,
                                                const int* __restrict__ src,
                                                const int* __restrict__ dst,
                                                const float* __restrict__ adj,
                                                int* __restrict__ gcur,
                                                int* __restrict__ ovfcnt,
                                                int4* __restrict__ ovflist,
                                                int2* __restrict__ coarse) {
    __shared__ __align__(16) char smem[16384];
    int tid = threadIdx.x;
    int bid = blockIdx.x;

    if (bid < CHW) {
        // ---- binning role (register-staged chunk, per-block run reservation) ----
        int* h = (int*)smem;            // NBUCK counts
        int* cur = h + NBUCK;           // NBUCK cursors
        for (int i = tid; i < NBUCK; i += 512) h[i] = 0;
        __syncthreads();

        int e0 = bid * CH, e1 = min(e0 + CH, N_EDGES);
        int dreg[CITER], sreg[CITER];
        float areg[CITER];
        #pragma unroll
        for (int it = 0; it < CITER; ++it) {
            int e = e0 + tid + it * 512;
            dreg[it] = -1;
            if (e < e1) {
                dreg[it] = __builtin_nontemporal_load(&dst[e]);
                sreg[it] = __builtin_nontemporal_load(&src[e]);
                areg[it] = __builtin_nontemporal_load(&adj[e]);
                atomicAdd(&h[dreg[it] >> 6], 1);
            }
        }
        __syncthreads();

        for (int c = tid; c < NBUCK; c += 512) {
            int hc = h[c];
            if (hc) cur[c] = atomicAdd(&gcur[c * PAD], hc);
        }
        __syncthreads();

        #pragma unroll
        for (int it = 0; it < CITER; ++it) {
            if (dreg[it] >= 0) {
                int c = dreg[it] >> 6;
                int pos = atomicAdd(&cur[c], 1);
                if (pos < CAP) {
                    coarse[c * CAP + pos] =
                        make_int2(sreg[it] | ((dreg[it] & 63) << 17),
                                  __float_as_int(areg[it]));
                } else {
                    int op = atomicAdd(ovfcnt, 1);
                    if (op < OVFMAX)
                        ovflist[op] = make_int4(sreg[it], dreg[it],
                                                __float_as_int(areg[it]), 0);
                }
            }
        }
    } else {
        // ---- GEMM role: support(bf16) = X @ W ----
        float4* wsh = (float4*)smem;    // 64x16 float4 = 16 KB
        const float4* w4 = (const float4*)w;
        for (int i = tid; i < 64 * 16; i += 512) wsh[i] = w4[i];
        __syncthreads();

        int idx = (bid - CHW) * 512 + tid;
        if (idx < GEMM_THREADS) {
            int rowpair = idx >> 4;
            int c4 = idx & 15;
            long r0 = (long)rowpair * 2;
            const float4* xr0 = (const float4*)(x + r0 * D);
            const float4* xr1 = (const float4*)(x + (r0 + 1) * D);

            float4 a0 = make_float4(0.f, 0.f, 0.f, 0.f);
            float4 a1 = make_float4(0.f, 0.f, 0.f, 0.f);
            #pragma unroll 4
            for (int k4 = 0; k4 < 16; ++k4) {
                float4 xv0 = xr0[k4];
                float4 xv1 = xr1[k4];
                float4 w0 = wsh[(4 * k4 + 0) * 16 + c4];
                float4 w1 = wsh[(4 * k4 + 1) * 16 + c4];
                float4 w2 = wsh[(4 * k4 + 2) * 16 + c4];
                float4 w3 = wsh[(4 * k4 + 3) * 16 + c4];
                a0 += w0 * xv0.x + w1 * xv0.y + w2 * xv0.z + w3 * xv0.w;
                a1 += w0 * xv1.x + w1 * xv1.y + w2 * xv1.z + w3 * xv1.w;
            }
            ushort4* s4 = (ushort4*)support;
            s4[r0 * 16 + c4] = make_ushort4(f2bf(a0.x), f2bf(a0.y), f2bf(a0.z), f2bf(a0.w));
            s4[(r0 + 1) * 16 + c4] = make_ushort4(f2bf(a1.x), f2bf(a1.y), f2bf(a1.z), f2bf(a1.w));
        }
    }
}

// ---------------- bgather: single-pass stage+count, LDS->LDS sort, wide gather ----
// R8 structure with ONE change: coarse is read ONCE (staged to sRaw while
// counting); phase B sorts LDS->LDS. Scan ladder, gather loop, epilogue are
// byte-identical to the R8 best.
__global__ __launch_bounds__(GT) void gcn_bgather(const unsigned short* __restrict__ support,
                                                  const int2* __restrict__ coarse,
                                                  const int* __restrict__ gcur,
                                                  const int* __restrict__ ovfcnt,
                                                  const int4* __restrict__ ovflist,
                                                  const float* __restrict__ bias,
                                                  float* __restrict__ out) {
    __shared__ int2 sRaw[SMAX];     // 16 KB raw staged edges (arrival order)
    __shared__ int2 sE[SMAX];       // 16 KB sorted edges
    __shared__ int cntS[BN], loffS[BN], curS[BN];

    int tid = threadIdx.x, wv = tid >> 6, lane = tid & 63;
    int b = blockIdx.x;
    int tot = min(gcur[b * PAD], CAP);      // bucket edge count (post-binning cursor)
    const int2* ce = coarse + (long)b * CAP;

    if (tid < BN) cntS[tid] = 0;
    __syncthreads();

    // stage + count in one global pass (coarse read exactly once)
    for (int e = tid; e < tot; e += GT) {
        int2 ed = ce[e];
        sRaw[e] = ed;
        atomicAdd(&cntS[(ed.x >> 17) & 63], 1);
    }
    __syncthreads();

    // scan 64 counters (proven ladder, unchanged)
    if (tid < BN) loffS[tid] = cntS[tid];
    __syncthreads();
    for (int off = 1; off < BN; off <<= 1) {
        int t = 0;
        if (tid < BN && tid >= off) t = loffS[tid - off];
        __syncthreads();
        if (tid < BN && tid >= off) loffS[tid] += t;
        __syncthreads();
    }
    if (tid < BN) {
        int excl = loffS[tid] - cntS[tid];
        loffS[tid] = excl;
        curS[tid] = excl;
    }
    __syncthreads();

    // phase B: place edges LDS->LDS per-node-sorted (pos < tot <= SMAX always)
    for (int e = tid; e < tot; e += GT) {
        int2 ed = sRaw[e];
        int nl = (ed.x >> 17) & 63;
        int pos = atomicAdd(&curS[nl], 1);
        sE[pos] = ed;
    }
    __syncthreads();

    // gather: wave wv owns local nodes [wv*8, wv*8+8)
    int eg = lane >> 4;      // edge sub-slot 0..3
    int L  = lane & 15;      // feature quad 0..15
    const uint2* sup2 = (const uint2*)support;     // 8 B = 4 bf16 features
    const float4* bias4 = (const float4*)bias;
    float4* out4 = (float4*)out;
    float4 bv = bias4[L];

    for (int nl = wv * 8; nl < wv * 8 + 8; ++nl) {
        int start = loffS[nl];
        int avail = cntS[nl];
        float4 acc = make_float4(0.f, 0.f, 0.f, 0.f);
        #pragma unroll 2
        for (int j = 0; j < avail; j += 16) {
            #pragma unroll
            for (int q = 0; q < 4; ++q) {
                int ei = j + q * 4 + eg;
                int2 ed = sE[start + min(ei, avail - 1)];
                float wgt = (ei < avail) ? __int_as_float(ed.y) : 0.f;
                uint2 p = sup2[(long)(ed.x & 0x1FFFF) * 16 + L];
                acc.x += wgt * __uint_as_float(p.x << 16);
                acc.y += wgt * __uint_as_float(p.x & 0xFFFF0000u);
                acc.z += wgt * __uint_as_float(p.y << 16);
                acc.w += wgt * __uint_as_float(p.y & 0xFFFF0000u);
            }
        }
        // reduce across the 4 edge-slot groups
        acc.x += __shfl_xor(acc.x, 16, 64); acc.y += __shfl_xor(acc.y, 16, 64);
        acc.z += __shfl_xor(acc.z, 16, 64); acc.w += __shfl_xor(acc.w, 16, 64);
        acc.x += __shfl_xor(acc.x, 32, 64); acc.y += __shfl_xor(acc.y, 32, 64);
        acc.z += __shfl_xor(acc.z, 32, 64); acc.w += __shfl_xor(acc.w, 32, 64);
        int n = b * BN + nl;
        if (lane < 16 && n < N_NODES) {
            float4 r = make_float4(acc.x + bv.x, acc.y + bv.y,
                                   acc.z + bv.z, acc.w + bv.w);
            out4[(long)n * 16 + L] = r;
        }
    }

    // overflow tail (correctness only; ovfcnt == 0 for this input -> one load)
    __syncthreads();
    int no = min(*ovfcnt, OVFMAX);
    for (int i = wv; i < no; i += GT / 64) {
        int4 ed = ovflist[i];
        if ((ed.y >> 6) == b) {
            float v = __int_as_float(ed.z) * bf2f(support[(long)ed.x * D + lane]);
            atomicAdd(&out[(long)ed.y * D + lane], v);
        }
    }
}

extern "C" void kernel_launch(void* const* d_in, const int* in_sizes, int n_in,
                              void* d_out, int out_size, void* d_ws, size_t ws_size,
                              hipStream_t stream) {
    const float* x      = (const float*)d_in[0];
    const float* weight = (const float*)d_in[1];
    const float* bias   = (const float*)d_in[2];
    const float* adj    = (const float*)d_in[3];
    const int*   src    = (const int*)d_in[4];
    const int*   dst    = (const int*)d_in[5];
    float* out = (float*)d_out;

    unsigned short* support = (unsigned short*)d_ws;          // 12,800,000 B
    int2* coarse = (int2*)(support + (long)N_NODES * D);      // NBUCK*CAP*8 = 25,608,192 B
    int*  gcur   = (int*)(coarse + (long)NBUCK * CAP);        // NBUCK*PAD*4 = 100,032 B
    int*  ovfcnt = gcur + NBUCK * PAD;                        // 16 B reserved
    int4* ovflist = (int4*)(ovfcnt + 4);                      // 524,288 B

    hipMemsetAsync(gcur, 0, NBUCK * PAD * sizeof(int) + 16, stream);
    hipLaunchKernelGGL(gcn_main, dim3(NBLK), dim3(512), 0, stream,
                       x, weight, support, src, dst, adj, gcur, ovfcnt, ovflist, coarse);
    hipLaunchKernelGGL(gcn_bgather, dim3(NBUCK), dim3(GT), 0, stream,
                       support, coarse, gcur, ovfcnt, ovflist, bias, out);
}